// Round 4
// baseline (239.611 us; speedup 1.0000x reference)
//
#include <hip/hip_runtime.h>

// BlockSample R10: R6 structure + system-scope write-through stores (sc0 sc1 nt).
//
// Evidence chain: R6 (comb)/R7 (linear)/R8 (no-LDS dep-free)/R9 (NT) all give
// kernel ~67-72us -> issue side exonerated. Fill's WRITE_SIZE is exactly its
// own 906MB at 6.6 TB/s -> L3 (256MB) is full of dirty poison when our kernel
// starts. Theory: every output-line allocation pairs with a dirty-victim
// writeback -> L3 slot traffic ~2x our bytes -> pattern-independent ~70us.
// NT store can't bypass a dirty-hit (must merge). sc0 sc1 system-scope store
// writes through AND invalidates the dirty poison line (fully covered by our
// 1KB wave stores) -> poison bytes dropped, kernel carries only 226.5MB.
// Prediction: kernel 70 -> ~40us, dur_us -> 195-210. If unchanged: ROOFLINE
// (compulsory-traffic floor + harness overhead).

#define BB 8
#define CC 192
#define HH 48
#define WW 48
#define G   16                 // channels per block
#define NCHG (CC / G)          // 12
#define YT  3                  // y's per block
#define NYG (HH / YT)          // 16
#define NROW (YT + 3)          // 6 staged rows per channel
#define PITCH 55               // 3 left pad + 48 + 4 spare; odd -> conflict-free
#define NBLK (BB * NCHG * NYG) // 1536 blocks = 6/CU exactly
#define NXCD 8

typedef float vfloat4 __attribute__((ext_vector_type(4)));

__device__ __forceinline__ void store_wt(vfloat4* addr, vfloat4 v) {
    // system-scope write-through + non-temporal: drop dirty poison lines
    // instead of pairing each allocation with a victim writeback.
    asm volatile("global_store_dwordx4 %0, %1, off sc0 sc1 nt"
                 :: "v"(addr), "v"(v) : "memory");
}

__global__ __launch_bounds__(256) void
blocksample_kernel(const float* __restrict__ in, float* __restrict__ out) {
    // XCD swizzle: contiguous (b,chg,yg) span per XCD; yg fastest so adjacent
    // tiles (sharing 3 halo rows) hit the same L2.
    const int id    = blockIdx.x;
    const int xcd   = id & (NXCD - 1);
    const int g     = xcd * (NBLK / NXCD) + (id >> 3);

    const int yg  = g % NYG;
    const int chg = (g / NYG) % NCHG;
    const int b   = g / (NYG * NCHG);
    const int y0  = yg * YT;

    __shared__ float lds[G * NROW * PITCH];       // 16 x 6 x 55 x 4B = 21,120 B

    const int t = threadIdx.x;

    // 1) zero the read halo: cols {1,2,51} of each of the 96 rows.
    for (int k = t; k < G * NROW * 3; k += 256) {
        const int rc = k / 3;
        const int m  = k - rc * 3;
        const int c  = (m == 0) ? 1 : ((m == 1) ? 2 : 51);
        lds[rc * PITCH + c] = 0.0f;
    }

    // 2) fill interior with float4 loads: rc = ch*NROW + dyr covers rows
    //    y0-3 .. y0+2 per channel; OOB rows written as zeros.
    const float* inb = in + ((size_t)(b * CC + chg * G) * HH) * WW;
    for (int f = t; f < G * NROW * (WW / 4); f += 256) {
        const int rc  = f / (WW / 4);             // 0..95
        const int c4  = f - rc * (WW / 4);        // 0..11
        const int ch  = rc / NROW;
        const int dyr = rc - ch * NROW;
        const int row = y0 - 3 + dyr;
        vfloat4 val = (vfloat4)(0.0f);
        if (row >= 0 && row < HH)
            val = *(const vfloat4*)(inb + ((size_t)(ch * HH + row)) * WW + c4 * 4);
        float* dst = lds + rc * PITCH + 3 + c4 * 4;
        dst[0] = val.x; dst[1] = val.y; dst[2] = val.z; dst[3] = val.w;
    }
    __syncthreads();

    // 3) stores: lane l -> (ch = l>>2, i = l&3); wave w covers x = w,w+4,...
    //    One 1KB-contiguous write-through store per (y,x).
    const int w  = t >> 6;
    const int l  = t & 63;
    const int i  = l & 3;
    const int ch = l >> 2;
    const float* lbase = lds + (ch * NROW + i) * PITCH;

    vfloat4* outb = (vfloat4*)out
        + ((size_t)((b * HH + y0) * WW) * CC + chg * G) * 4 + l;

    for (int dy = 0; dy < YT; ++dy) {
        const float* lrow = lbase + dy * PITCH;
        vfloat4* orow = outb + (size_t)dy * (WW * CC * 4);
        for (int x = w; x < WW; x += 4) {
            const float* p = lrow + (x + 1);      // input col x-2 at LDS col x+1
            vfloat4 v;
            v.x = p[0];
            v.y = p[1];
            v.z = p[2];
            v.w = p[3];
            if (i == 3) { v.z = 0.0f; v.w = 0.0f; }  // masked taps (3,2),(3,3)
            store_wt(&orow[(size_t)x * (CC * 4)], v);
        }
    }
}

extern "C" void kernel_launch(void* const* d_in, const int* in_sizes, int n_in,
                              void* d_out, int out_size, void* d_ws, size_t ws_size,
                              hipStream_t stream) {
    const float* in = (const float*)d_in[0];
    float* out = (float*)d_out;
    blocksample_kernel<<<dim3(NBLK), dim3(256), 0, stream>>>(in, out);
}

// Round 5
// 229.100 us; speedup vs baseline: 1.0459x; 1.0459x over previous
//
#include <hip/hip_runtime.h>

// BlockSample R11: R7 base + PER-WAVE-LINEAR store sweep. Single-variable change.
//
// Evidence chain: R6 (comb)/R7 ("linear" block-level)/R8 (no-LDS)/R9 (nt)/
// R10 (sc0 sc1 nt) all give fill-normalized Delta = dur_us - fill ~= 91-99us.
// Cache policy, LDS, barriers, occupancy, block-level store layout: all null.
// Remaining difference vs the 6.7 TB/s harness fill: the fill's stores are
// per-WAVE linear (consecutive 1KB stores per wave); ALL our kernels had each
// wave striding 12KB between 1KB chunks (R7's px-sweep with fixed slot).
// -> DRAM open-page locality. Fix: wave w owns pixels {2w, 2w+1} and sweeps
// SLOTS: instruction n writes slot (n%12)*64+l of pixel 2w+n/12; per-wave
// address step = +1KB for 24 consecutive stores (24KB linear span per wave,
// 288KB per block). Fill phase / values / masking byte-identical to R7.
// LDS store-read: row=(n%12)*64+l, pitch 33 -> bank (l+c)%32, 2-way = free.
// Prediction: Delta 95 -> 65-75 (dur_us ~200-212). If Delta >= 88: ROOFLINE.

#define CC 192
#define HH 48
#define WW 48
#define PXB 24              // pixels per task (x-chunk)
#define PITCH 33            // 32 staged cols + 1 spare
#define TPB 768             // 12 waves; fill: t <-> (ch=t>>5 +24q, i=(t>>3)&3)
#define NBLK 256
#define LDS_BYTES (CC * 4 * PITCH * 4)   // 768 rows x 33 floats x 4B = 101376

typedef float vfloat4 __attribute__((ext_vector_type(4)));

__global__ __launch_bounds__(TPB) void
blocksample_kernel(const float* __restrict__ in, float* __restrict__ out) {
    extern __shared__ float lds[];
    const int t  = threadIdx.x;
    const int id = blockIdx.x;
    const int b  = id & 7;         // XCD-partitioned batch
    const int k  = id >> 3;        // 0..31 within XCD
    const int xh = k & 1;          // x-chunk
    const int y0 = k >> 1;         // task r: y = y0 + 16*r, r = 0..2
    const int x0 = PXB * xh;

    // Fill decode (task-invariant): thread t loads float4 slot q4 of LDS rows
    // rc = (t>>3) + 96q, q = 0..7. LDS row rc holds (ch = rc>>2, i = rc&3):
    // input row y+i-3, global cols [x0-4, x0+28).
    const int q4   = t & 7;
    const int irow = (t >> 3) & 3;
    const int ch0  = t >> 5;                   // channel = ch0 + 24q
    const int colg = x0 - 4 + 4 * q4;          // global col of this float4
    const bool colok = (colg >= 0) & (colg <= WW - 4);
    const float* inb = in + (size_t)b * CC * HH * WW;

    vfloat4 stage[8];

#define LOADTASK(yy) do {                                                     \
        const int row  = (yy) + irow - 3;                                     \
        const bool ok  = (row >= 0) & colok;                                  \
        const int rowc = (row >= 0) ? row : 0;                                \
        const int colc = colok ? colg : 0;                                    \
        const float* p = inb + ((size_t)(ch0 * HH + rowc)) * WW + colc;       \
        _Pragma("unroll")                                                     \
        for (int q = 0; q < 8; ++q) {                                         \
            stage[q] = *(const vfloat4*)(p + (size_t)q * 24 * HH * WW);       \
            if (!ok) stage[q] = (vfloat4)(0.0f);                              \
        }                                                                     \
    } while (0)

    LOADTASK(y0);                  // prologue: task 0 loads in flight

    const int w  = t >> 6;         // wave 0..11 -> owns pixels 2w, 2w+1
    const int l  = t & 63;
    const bool masked = (l & 3) == 3;   // slot i==3 -> taps j=2,3 zeroed
    float* dst0 = lds + ((size_t)(t >> 3)) * PITCH + 4 * q4;

    int y = y0;
    for (int r = 0; r < 3; ++r) {
        // stage -> LDS
        #pragma unroll
        for (int q = 0; q < 8; ++q) {
            float* d = dst0 + (size_t)q * 96 * PITCH;
            d[0] = stage[q].x; d[1] = stage[q].y;
            d[2] = stage[q].z; d[3] = stage[q].w;
        }
        __syncthreads();

        if (r < 2) LOADTASK(y + 16);   // T14: issue next task's loads early

        // PER-WAVE-LINEAR store sweep: instruction n writes slot s=(n%12)*64+l
        // of pixel px=2w+n/12. Wave address step = +1KB, 24 consecutive 1KB
        // stores = 24KB linear span per wave; block tiles 288KB contiguously.
        // Value: LDS row s (= ch*4+i), cols px+2..px+5 <-> in cols x-2..x+1.
        vfloat4* op = (vfloat4*)out
            + ((size_t)((b * HH + y) * WW + x0)) * (CC * 4);
        #pragma unroll
        for (int n = 0; n < 24; ++n) {
            const int px = 2 * w + n / 12;
            const int s  = (n % 12) * 64 + l;
            const float* p = lds + (size_t)s * PITCH + (px + 2);
            vfloat4 v;
            v.x = p[0]; v.y = p[1]; v.z = p[2]; v.w = p[3];
            if (masked) { v.z = 0.0f; v.w = 0.0f; }
            op[(size_t)px * (CC * 4) + s] = v;
        }
        __syncthreads();               // all LDS reads done before next overwrite
        y += 16;
    }
#undef LOADTASK
}

extern "C" void kernel_launch(void* const* d_in, const int* in_sizes, int n_in,
                              void* d_out, int out_size, void* d_ws, size_t ws_size,
                              hipStream_t stream) {
    static bool inited = false;
    if (!inited) {
        hipFuncSetAttribute(reinterpret_cast<const void*>(blocksample_kernel),
                            hipFuncAttributeMaxDynamicSharedMemorySize, LDS_BYTES);
        inited = true;
    }
    const float* in = (const float*)d_in[0];
    float* out = (float*)d_out;
    blocksample_kernel<<<dim3(NBLK), dim3(TPB), LDS_BYTES, stream>>>(in, out);
}